// Round 1
// baseline (50.713 us; speedup 1.0000x reference)
//
#include <hip/hip_runtime.h>

// loss = mean_i max(0, 0.1 - (a[i] - b[i])), N = 33554432 fp32 elements per input.
// Memory-bound streaming reduce: ~268 MB read -> ~43 us roofline @6.3 TB/s.

constexpr float MARGIN = 0.1f;

// Stage 1: grid-stride float4 loads, per-thread fp32 accumulate,
// wave shuffle reduce (width 64), cross-wave LDS reduce, one partial per block.
__global__ void hinge_partial_kernel(const float* __restrict__ a,
                                     const float* __restrict__ b,
                                     float* __restrict__ partials,
                                     int n4) {
    const float4* __restrict__ a4 = reinterpret_cast<const float4*>(a);
    const float4* __restrict__ b4 = reinterpret_cast<const float4*>(b);

    float acc = 0.0f;
    const int stride = gridDim.x * blockDim.x;
    for (int i = blockIdx.x * blockDim.x + threadIdx.x; i < n4; i += stride) {
        float4 x = a4[i];
        float4 y = b4[i];
        acc += fmaxf(0.0f, MARGIN - (x.x - y.x));
        acc += fmaxf(0.0f, MARGIN - (x.y - y.y));
        acc += fmaxf(0.0f, MARGIN - (x.z - y.z));
        acc += fmaxf(0.0f, MARGIN - (x.w - y.w));
    }

    // wave (64-lane) butterfly reduce
    #pragma unroll
    for (int off = 32; off > 0; off >>= 1)
        acc += __shfl_down(acc, off, 64);

    __shared__ float sdata[4];  // 256 threads / 64 lanes = 4 waves
    const int lane = threadIdx.x & 63;
    const int wave = threadIdx.x >> 6;
    if (lane == 0) sdata[wave] = acc;
    __syncthreads();
    if (threadIdx.x == 0)
        partials[blockIdx.x] = sdata[0] + sdata[1] + sdata[2] + sdata[3];
}

// Stage 2: one block reduces the block partials and writes the mean.
__global__ void hinge_finalize_kernel(const float* __restrict__ partials,
                                      float* __restrict__ out,
                                      int nparts,
                                      float inv_n) {
    float acc = 0.0f;
    for (int i = threadIdx.x; i < nparts; i += blockDim.x)
        acc += partials[i];

    #pragma unroll
    for (int off = 32; off > 0; off >>= 1)
        acc += __shfl_down(acc, off, 64);

    __shared__ float sdata[4];
    const int lane = threadIdx.x & 63;
    const int wave = threadIdx.x >> 6;
    if (lane == 0) sdata[wave] = acc;
    __syncthreads();
    if (threadIdx.x == 0)
        out[0] = (sdata[0] + sdata[1] + sdata[2] + sdata[3]) * inv_n;
}

extern "C" void kernel_launch(void* const* d_in, const int* in_sizes, int n_in,
                              void* d_out, int out_size, void* d_ws, size_t ws_size,
                              hipStream_t stream) {
    const float* a = reinterpret_cast<const float*>(d_in[0]);  // alphas_part_max
    const float* b = reinterpret_cast<const float*>(d_in[1]);  // alphas_org
    float* out = reinterpret_cast<float*>(d_out);
    float* partials = reinterpret_cast<float*>(d_ws);

    const int n = in_sizes[0];        // 33554432, divisible by 4
    const int n4 = n >> 2;

    const int block = 256;
    const int grid = 2048;            // 256 CUs * 8 blocks/CU; grid-stride the rest

    hinge_partial_kernel<<<grid, block, 0, stream>>>(a, b, partials, n4);
    hinge_finalize_kernel<<<1, block, 0, stream>>>(partials, out, grid,
                                                   1.0f / static_cast<float>(n));
}

// Round 2
// 48.293 us; speedup vs baseline: 1.0501x; 1.0501x over previous
//
#include <hip/hip_runtime.h>

// loss = mean_i max(0, 0.1 - (a[i] - b[i])), N = 33554432 fp32 per input.
// Inputs (256 MiB total) straddle L3 exactly -> ~50% L3 hit across replays.
// Latency-bound at R1 (12 VGPR, 1 iter of loads in flight). Fix: unroll x4,
// 4 accumulators, 8 independent float4 loads issued per iteration.

constexpr float MARGIN = 0.1f;

__device__ __forceinline__ float hinge4(float4 x, float4 y) {
    return fmaxf(0.0f, MARGIN - (x.x - y.x))
         + fmaxf(0.0f, MARGIN - (x.y - y.y))
         + fmaxf(0.0f, MARGIN - (x.z - y.z))
         + fmaxf(0.0f, MARGIN - (x.w - y.w));
}

__global__ void hinge_partial_kernel(const float* __restrict__ a,
                                     const float* __restrict__ b,
                                     float* __restrict__ partials,
                                     int n4) {
    const float4* __restrict__ a4 = reinterpret_cast<const float4*>(a);
    const float4* __restrict__ b4 = reinterpret_cast<const float4*>(b);

    const int stride = gridDim.x * blockDim.x;
    int i = blockIdx.x * blockDim.x + threadIdx.x;

    float acc0 = 0.0f, acc1 = 0.0f, acc2 = 0.0f, acc3 = 0.0f;

    // Main unrolled loop: 8 independent 16B loads in flight per iteration.
    for (; i + 3 * stride < n4; i += 4 * stride) {
        float4 x0 = a4[i];
        float4 x1 = a4[i + stride];
        float4 x2 = a4[i + 2 * stride];
        float4 x3 = a4[i + 3 * stride];
        float4 y0 = b4[i];
        float4 y1 = b4[i + stride];
        float4 y2 = b4[i + 2 * stride];
        float4 y3 = b4[i + 3 * stride];
        acc0 += hinge4(x0, y0);
        acc1 += hinge4(x1, y1);
        acc2 += hinge4(x2, y2);
        acc3 += hinge4(x3, y3);
    }
    // Tail (not taken for N=2^25 with grid 2048x256, kept for generality).
    for (; i < n4; i += stride)
        acc0 += hinge4(a4[i], b4[i]);

    float acc = (acc0 + acc1) + (acc2 + acc3);

    // wave (64-lane) shuffle reduce
    #pragma unroll
    for (int off = 32; off > 0; off >>= 1)
        acc += __shfl_down(acc, off, 64);

    __shared__ float sdata[4];  // 256 threads / 64 lanes = 4 waves
    const int lane = threadIdx.x & 63;
    const int wave = threadIdx.x >> 6;
    if (lane == 0) sdata[wave] = acc;
    __syncthreads();
    if (threadIdx.x == 0)
        partials[blockIdx.x] = sdata[0] + sdata[1] + sdata[2] + sdata[3];
}

__global__ void hinge_finalize_kernel(const float* __restrict__ partials,
                                      float* __restrict__ out,
                                      int nparts,
                                      float inv_n) {
    float acc = 0.0f;
    for (int i = threadIdx.x; i < nparts; i += blockDim.x)
        acc += partials[i];

    #pragma unroll
    for (int off = 32; off > 0; off >>= 1)
        acc += __shfl_down(acc, off, 64);

    __shared__ float sdata[4];
    const int lane = threadIdx.x & 63;
    const int wave = threadIdx.x >> 6;
    if (lane == 0) sdata[wave] = acc;
    __syncthreads();
    if (threadIdx.x == 0)
        out[0] = (sdata[0] + sdata[1] + sdata[2] + sdata[3]) * inv_n;
}

extern "C" void kernel_launch(void* const* d_in, const int* in_sizes, int n_in,
                              void* d_out, int out_size, void* d_ws, size_t ws_size,
                              hipStream_t stream) {
    const float* a = reinterpret_cast<const float*>(d_in[0]);  // alphas_part_max
    const float* b = reinterpret_cast<const float*>(d_in[1]);  // alphas_org
    float* out = reinterpret_cast<float*>(d_out);
    float* partials = reinterpret_cast<float*>(d_ws);

    const int n = in_sizes[0];        // 33554432, divisible by 4
    const int n4 = n >> 2;

    const int block = 256;
    const int grid = 2048;            // 8 blocks/CU; each thread: 16 float4 iters

    hinge_partial_kernel<<<grid, block, 0, stream>>>(a, b, partials, n4);
    hinge_finalize_kernel<<<1, block, 0, stream>>>(partials, out, grid,
                                                   1.0f / static_cast<float>(n));
}